// Round 9
// baseline (1993.851 us; speedup 1.0000x reference)
//
#include <hip/hip_runtime.h>
#include <stdint.h>

typedef unsigned long long u64;
typedef unsigned int u32;

// anchor (w,h) per a = ratio_idx*3 + scale_idx ; ratios (.5,1,2), scales (8,16,32)
__constant__ float c_aw[9] = {184.f,368.f,736.f,128.f,256.f,512.f, 88.f,176.f,352.f};
__constant__ float c_ah[9] = { 96.f,192.f,384.f,128.f,256.f,512.f,176.f,352.f,704.f};

// -------- w1 reorder: w1[co][ci*9+k] -> wt2[g][ci][k][m], co = g*8+m ----------
// coalesced reads (e linear over w1), scattered-but-local writes
__global__ __launch_bounds__(256) void transpose_k(const float* __restrict__ w1,
                                                   float* __restrict__ wt2) {
  int e = blockIdx.x * 256 + threadIdx.x;   // < 2359296 exactly
  int q = e % 4608;          // ci*9+k
  int co = e / 4608;
  int ci = q / 9;
  int k = q - ci * 9;
  int g = co >> 3, m = co & 7;
  wt2[(((size_t)g * 512 + ci) * 9 + k) * 8 + m] = w1[e];
}

// ---------------- conv1: x(4,512,96,160) * w s2 p1 -> feat(4,512,48,80)
// block tile: 32co x 4oh x 80ow, 4 waves, wave = one co-group of 8.
// Double-buffered LDS (4-ci chunks), ONE barrier per step:
//   barrier -> ds_write buf[t+1] -> issue loads t+2 -> compute buf[t]
// accumulation order (ci 0..511 ascending, kh, kw inner) bitwise matches all
// passing rounds.
__global__ __launch_bounds__(256, 3) void conv1_k(const float* __restrict__ x,
                                                  const float* __restrict__ wt2,
                                                  const float* __restrict__ b1,
                                                  float* __restrict__ feat) {
  __shared__ float xs[2][4 * 9 * 164];   // 2 x 23616 B = 47232 B
  const int tid = threadIdx.x;
  const int lane = tid & 63;
  const int wv = __builtin_amdgcn_readfirstlane(tid >> 6);   // wave id 0..3
  const int owg = lane & 15;          // 16 groups of 5 ow
  const int ohl = lane >> 4;          // 0..3
  const int n = blockIdx.z;
  const int gg = blockIdx.x * 4 + wv; // global co-group, co = gg*8+m
  const int oh0 = blockIdx.y * 4;
  const int ih_base = 2 * oh0 - 1;

  // ---- step-invariant staging descriptors (6 strided passes over 1449 slots) ----
  int soff[6], loff[6];
  float okf[6];
  bool act[6];
#pragma unroll
  for (int it = 0; it < 6; ++it) {
    int e2 = tid + 256 * it;
    act[it] = (e2 < 1449);
    int e = act[it] ? e2 : 0;
    int ih = e / 161;
    int c = e - ih * 161;
    int gih = ih_base + ih;
    int giw = c - 1;
    bool ok = act[it] && ((unsigned)gih < 96u) && ((unsigned)giw < 160u);
    soff[it] = min(max(gih, 0), 95) * 160 + min(max(giw, 0), 159);
    loff[it] = ih * 164 + c;
    okf[it] = ok ? 1.f : 0.f;
  }

  float acc[8][5];
#pragma unroll
  for (int m = 0; m < 8; ++m)
#pragma unroll
    for (int j = 0; j < 5; ++j) acc[m][j] = 0.f;

  const float* xb = x + (size_t)n * 512 * 96 * 160;
  const float* wgb = wt2 + (size_t)gg * 512 * 72;   // [ci][k(9)][m(8)]

  // prologue: load chunk0 -> write buf0 -> load chunk1 into regs
  float r[6][4];
#pragma unroll
  for (int it = 0; it < 6; ++it)
#pragma unroll
    for (int ci = 0; ci < 4; ++ci)
      r[it][ci] = xb[(size_t)ci * 15360 + soff[it]];
#pragma unroll
  for (int it = 0; it < 6; ++it) {
    if (act[it]) {
      const float m_ = okf[it];
#pragma unroll
      for (int ci = 0; ci < 4; ++ci)
        xs[0][loff[it] + ci * 1476] = m_ * r[it][ci];   // 1476 = 9*164
    }
  }
#pragma unroll
  for (int it = 0; it < 6; ++it)
#pragma unroll
    for (int ci = 0; ci < 4; ++ci)
      r[it][ci] = xb[(size_t)(4 + ci) * 15360 + soff[it]];

  for (int t = 0; t < 128; ++t) {
    __syncthreads();   // step t-1 fully done: buf[t&1] writes visible,
                       // buf[(t+1)&1] no longer being read
    const int cur = t & 1;
    if (t < 127) {     // write chunk t+1 (held in r) into the other buffer
#pragma unroll
      for (int it = 0; it < 6; ++it) {
        if (act[it]) {
          const float m_ = okf[it];
#pragma unroll
          for (int ci = 0; ci < 4; ++ci)
            xs[cur ^ 1][loff[it] + ci * 1476] = m_ * r[it][ci];
        }
      }
    }
    if (t < 126) {     // issue loads for chunk t+2; fly under compute below
      const float* xn = xb + (size_t)(t + 2) * 4 * 15360;
#pragma unroll
      for (int it = 0; it < 6; ++it)
#pragma unroll
        for (int ci = 0; ci < 4; ++ci)
          r[it][ci] = xn[(size_t)ci * 15360 + soff[it]];
    }

    const int c0 = t * 4;
    for (int ci = 0; ci < 4; ++ci) {
      const float* wp = wgb + (size_t)(c0 + ci) * 72;   // wave-uniform
      const float* xrow = &xs[cur][(ci * 9 + 2 * ohl) * 164 + owg * 10];
#pragma unroll
      for (int kh = 0; kh < 3; ++kh) {
        float xv[12];
        const float* xr = xrow + kh * 164;
#pragma unroll
        for (int t2 = 0; t2 < 6; ++t2) {          // 8B-aligned b64 LDS reads
          float2 tt = *(const float2*)(xr + 2 * t2);
          xv[2 * t2] = tt.x; xv[2 * t2 + 1] = tt.y;
        }
#pragma unroll
        for (int kw = 0; kw < 3; ++kw) {
          const float* wk = wp + (kh * 3 + kw) * 8;
#pragma unroll
          for (int j = 0; j < 5; ++j) {
            const float xj = xv[kw + 2 * j];
            acc[0][j] += wk[0] * xj; acc[1][j] += wk[1] * xj;
            acc[2][j] += wk[2] * xj; acc[3][j] += wk[3] * xj;
            acc[4][j] += wk[4] * xj; acc[5][j] += wk[5] * xj;
            acc[6][j] += wk[6] * xj; acc[7][j] += wk[7] * xj;
          }
        }
      }
    }
  }
  // epilogue
  const int oh = oh0 + ohl;
  const int owb = owg * 5;
#pragma unroll
  for (int m = 0; m < 8; ++m) {
    const int co = gg * 8 + m;
    const float bv = b1[co];
    float* op = &feat[(((size_t)n * 512 + co) * 48 + oh) * 80 + owb];
#pragma unroll
    for (int j = 0; j < 5; ++j) op[j] = acc[m][j] + bv;
  }
}

// ---------------- fused heads: blocks [0,120) = conv2 (1x1 bbox), [120,312) = conv3 (3x3 cls)
__global__ __launch_bounds__(256) void heads_k(const float* __restrict__ feat,
                                               const float* __restrict__ wb,
                                               const float* __restrict__ bb,
                                               const float* __restrict__ wcg,
                                               const float* __restrict__ bc,
                                               float* __restrict__ deltas,
                                               float* __restrict__ s) {
  __shared__ float smem[5328];
  const int tid = threadIdx.x;

  if (blockIdx.x < 120) {
    // ---- conv2: 1x1, feat -> deltas[b][pos][36] ----
    float* fs  = smem;          // 16*128
    float* wsb = smem + 2048;   // 16*36
    const int blk = blockIdx.x;
    const int b = blk / 30;
    const int pos0 = (blk % 30) * 128;
    const int pl = tid >> 1, cg = tid & 1;
    const int cbase = cg * 18;
    float acc[18];
#pragma unroll
    for (int j = 0; j < 18; ++j) acc[j] = 0.f;
    const float* fb = feat + (size_t)b * 512 * 3840;

    for (int c0 = 0; c0 < 512; c0 += 16) {
      for (int e = tid; e < 16 * 128; e += 256)
        fs[e] = fb[(size_t)(c0 + (e >> 7)) * 3840 + pos0 + (e & 127)];
      for (int e = tid; e < 16 * 36; e += 256) {
        int ci = e / 36, c = e - ci * 36;
        wsb[e] = wb[(size_t)c * 512 + c0 + ci];
      }
      __syncthreads();
      for (int ci = 0; ci < 16; ++ci) {
        float xv = fs[ci * 128 + pl];
#pragma unroll
        for (int j = 0; j < 18; ++j) acc[j] += xv * wsb[ci * 36 + cbase + j];
      }
      __syncthreads();
    }
    size_t o = ((size_t)b * 3840 + pos0 + pl) * 36 + cbase;
#pragma unroll
    for (int j = 0; j < 18; ++j) deltas[o + j] = acc[j] + bb[cbase + j];
  } else {
    // ---- conv3: 3x3 p1, cls channels 9..17 -> s[b][pos*9+a] ----
    float (*fs)[3][84] = (float(*)[3][84])smem;           // 16*3*84 = 4032
    float (*wc)[9][9]  = (float(*)[9][9])(smem + 4032);   // 16*81 = 1296
    const int bid2 = blockIdx.x - 120;
    const int oh = bid2 % 48;
    const int b = bid2 / 48;
    const int pos = tid % 80;
    const int cg = tid / 80;          // 0..3 (cg==3 idle for compute)
    float acc[3] = {0.f, 0.f, 0.f};
    const float* fb = feat + (size_t)b * 512 * 3840;

    for (int c0 = 0; c0 < 512; c0 += 16) {
      for (int e = tid; e < 16 * 246; e += 256) {
        int ci = e / 246;
        int r = e - ci * 246;
        int ihl = r / 82;
        int iw = r - ihl * 82 - 1;
        int gih = oh - 1 + ihl;
        float v = 0.f;
        if ((unsigned)gih < 48u && (unsigned)iw < 80u)
          v = fb[(size_t)(c0 + ci) * 3840 + gih * 80 + iw];
        fs[ci][ihl][iw + 1] = v;
      }
      for (int e = tid; e < 16 * 81; e += 256) {
        int ci = e / 81;
        int r = e - ci * 81;
        int co = r / 9;
        int k = r - co * 9;
        wc[ci][co][k] = wcg[((size_t)(9 + co) * 512 + c0 + ci) * 9 + k];
      }
      __syncthreads();
      if (cg < 3) {
        const int cb = cg * 3;
        for (int ci = 0; ci < 16; ++ci) {
#pragma unroll
          for (int kh = 0; kh < 3; ++kh) {
#pragma unroll
            for (int kw = 0; kw < 3; ++kw) {
              float xv = fs[ci][kh][pos + kw];
              acc[0] += xv * wc[ci][cb + 0][kh * 3 + kw];
              acc[1] += xv * wc[ci][cb + 1][kh * 3 + kw];
              acc[2] += xv * wc[ci][cb + 2][kh * 3 + kw];
            }
          }
        }
      }
      __syncthreads();
    }
    if (cg < 3) {
      const int cb = cg * 3;
      size_t o = (size_t)b * 34560 + ((size_t)oh * 80 + pos) * 9 + cb;
#pragma unroll
      for (int j = 0; j < 3; ++j) s[o + j] = acc[j] + bc[9 + cb + j];
    }
  }
}

// ---------------- decode: anchors + deltas -> boxes, filtered score keys ----------------
__global__ __launch_bounds__(256) void decode_k(const float* __restrict__ deltas,
                                                const float* __restrict__ s,
                                                float* __restrict__ boxes,
                                                u64* __restrict__ keys) {
  const int g = blockIdx.x * 256 + threadIdx.x;  // < 138240 exactly
  const int b = g / 34560;
  const int i = g - b * 34560;
  const int pos = i / 9;
  const int a = i - pos * 9;
  const int h = pos / 80;
  const int w = pos - h * 80;
  const float gx = (float)(w * 32);
  const float gy = (float)(h * 32);
  const float aw = c_aw[a], ah = c_ah[a];
  const float x1a = 7.5f - 0.5f * (aw - 1.f);   // exact
  const float y1a = 7.5f - 0.5f * (ah - 1.f);   // exact
  const float ws_ = aw, hs_ = ah;               // x2-x1+1 exact
  const float cx = (gx + x1a) + 0.5f * ws_;     // exact
  const float cy = (gy + y1a) + 0.5f * hs_;     // exact

  const float* dp = &deltas[((size_t)b * 3840 + pos) * 36 + a * 4];
  const float d0 = dp[0], d1 = dp[1], d2 = dp[2], d3 = dp[3];
  const float pcx = __fadd_rn(__fmul_rn(d0, ws_), cx);
  const float pcy = __fadd_rn(__fmul_rn(d1, hs_), cy);
  const float pw = __fmul_rn(expf(d2), ws_);
  const float ph = __fmul_rn(expf(d3), hs_);
  float bx1 = __fsub_rn(pcx, __fmul_rn(0.5f, pw));
  float by1 = __fsub_rn(pcy, __fmul_rn(0.5f, ph));
  float bx2 = __fadd_rn(pcx, __fmul_rn(0.5f, pw));
  float by2 = __fadd_rn(pcy, __fmul_rn(0.5f, ph));
  bx1 = fminf(fmaxf(bx1, 0.f), 2559.f);
  by1 = fminf(fmaxf(by1, 0.f), 1535.f);
  bx2 = fminf(fmaxf(bx2, 0.f), 2559.f);
  by2 = fminf(fmaxf(by2, 0.f), 1535.f);
  const float bw = __fadd_rn(__fsub_rn(bx2, bx1), 1.f);
  const float bh = __fadd_rn(__fsub_rn(by2, by1), 1.f);
  float sc = s[g];
  if (!(bw >= 16.f && bh >= 16.f)) sc = -1e30f;

  float4 bo;
  bo.x = bx1; bo.y = by1; bo.z = bx2; bo.w = by2;
  *(float4*)&boxes[(size_t)g * 4] = bo;

  u32 sb = __float_as_uint(sc);
  u32 ou = (sb & 0x80000000u) ? ~sb : (sb | 0x80000000u);
  keys[g] = ((u64)ou << 32) | (u32)(~(u32)i);
}

// ---- fused select (exact rank-2000 threshold, 6-pass radix) + compact, per batch ----
// 4-way replicated histogram to cut same-bin LDS-atomic serialization.
__global__ __launch_bounds__(1024) void selcomp_k(const u64* __restrict__ keys,
                                                  u64* __restrict__ sel) {
  __shared__ u32 h4[4 * 2048];
  __shared__ int s_bin;
  __shared__ u32 s_above;
  __shared__ int sc;
  const int b = blockIdx.x;
  const int tid = threadIdx.x;
  const u64* kb = keys + (size_t)b * 34560;
  u64 prefix = 0, pmask = 0;
  int rank = 2000;
  const int rep = (tid & 3) * 2048;

#pragma unroll 1
  for (int pass = 0; pass < 6; ++pass) {
    int shift = 53 - 11 * pass;
    if (shift < 0) shift = 0;
#pragma unroll
    for (int q = 0; q < 8; ++q) h4[tid + 1024 * q] = 0;
    __syncthreads();
    for (int i = tid; i < 34560; i += 1024) {
      u64 k = kb[i];
      if ((k & pmask) == prefix)
        atomicAdd(&h4[rep + (u32)((k >> shift) & 2047ull)], 1u);
    }
    __syncthreads();
    // merge replicas into h4[0..2048)
    {
      int i = tid;
      if (i < 2048) h4[i] += h4[i + 2048] + h4[i + 4096] + h4[i + 6144];
      i = tid + 1024;
      if (i < 2048) h4[i] += h4[i + 2048] + h4[i + 4096] + h4[i + 6144];
    }
    __syncthreads();
    // suffix sum: h4[i] = count with bin >= i
    for (int off = 1; off < 2048; off <<= 1) {
      u32 t0, t1;
      { int i = tid;        t0 = h4[i] + ((i + off < 2048) ? h4[i + off] : 0u); }
      { int i = tid + 1024; t1 = h4[i] + ((i + off < 2048) ? h4[i + off] : 0u); }
      __syncthreads();
      h4[tid] = t0; h4[tid + 1024] = t1;
      __syncthreads();
    }
#pragma unroll
    for (int q = 0; q < 2; ++q) {
      int i = tid + 1024 * q;
      u32 Si = h4[i];
      u32 Sn = (i < 2047) ? h4[i + 1] : 0u;
      if ((int)Si >= rank && (int)Sn < rank) { s_bin = i; s_above = Sn; }
    }
    __syncthreads();
    rank -= (int)s_above;
    prefix |= ((u64)(u32)s_bin) << shift;
    pmask |= (2047ull << shift);
    __syncthreads();
  }
  // compact: keys >= prefix (exactly 2000, unordered)
  if (tid == 0) sc = 0;
  __syncthreads();
  for (int i = tid; i < 34560; i += 1024) {
    u64 k = kb[i];
    if (k >= prefix) {
      int p = atomicAdd(&sc, 1);
      sel[(size_t)b * 2048 + p] = k;
    }
  }
}

// ---------------- fused sort(2048) + greedy NMS per batch (256 thr: cheap barriers) ----
__global__ __launch_bounds__(256) void nms2_k(const u64* __restrict__ sel,
                                              const float* __restrict__ boxes,
                                              float* __restrict__ out) {
  __shared__ u64 K[2048];
  __shared__ float bx1[2000], by1[2000], bx2[2000], by2[2000], ar[2000];
  __shared__ unsigned char val[2000];
  __shared__ int s_pick, s_cur, s_cnt;
  const int b = blockIdx.x;
  const int tid = threadIdx.x;

  for (int i = tid; i < 2048; i += 256)
    K[i] = (i < 2000) ? sel[(size_t)b * 2048 + i] : 0ull;
  __syncthreads();
  // bitonic sort descending
  for (int k2 = 2; k2 <= 2048; k2 <<= 1) {
    for (int j = k2 >> 1; j > 0; j >>= 1) {
      for (int i = tid; i < 2048; i += 256) {
        int l = i ^ j;
        if (l > i) {
          u64 a = K[i], c = K[l];
          bool up = ((i & k2) == 0);
          if (up ? (a < c) : (a > c)) { K[i] = c; K[l] = a; }
        }
      }
      __syncthreads();
    }
  }
  // extract boxes/validity in score order
  for (int i = tid; i < 2000; i += 256) {
    u64 key = K[i];
    u32 ou = (u32)(key >> 32);
    int idx = (int)(~(u32)key);
    u32 sb = (ou & 0x80000000u) ? (ou & 0x7FFFFFFFu) : ~ou;
    float sc = __uint_as_float(sb);
    const float4 bo = *(const float4*)&boxes[((size_t)b * 34560 + idx) * 4];
    bx1[i] = bo.x; by1[i] = bo.y; bx2[i] = bo.z; by2[i] = bo.w;
    ar[i] = __fmul_rn(__fadd_rn(__fsub_rn(bo.z, bo.x), 1.f),
                      __fadd_rn(__fsub_rn(bo.w, bo.y), 1.f));
    val[i] = (sc > -5e29f) ? 1 : 0;
  }
  if (tid == 0) { s_cur = 0; s_cnt = 0; }
  __syncthreads();

  for (int t = 0; t < 300; ++t) {
    if (tid == 0) {
      int c = s_cur;
      while (c < 2000 && !val[c]) ++c;
      if (c < 2000) { s_pick = c; s_cur = c + 1; s_cnt = t + 1; }
      else s_pick = -1;
    }
    __syncthreads();
    const int p = s_pick;
    if (p < 0) break;
    const float px1 = bx1[p], py1 = by1[p], px2 = bx2[p], py2 = by2[p], pa = ar[p];
    if (tid == 0) {
      float* row = out + ((size_t)b * 300 + t) * 5;
      row[0] = (float)b; row[1] = px1; row[2] = py1; row[3] = px2; row[4] = py2;
    }
    for (int jj = p + 1 + tid; jj < 2000; jj += 256) {
      if (val[jj]) {
        float iw = __fadd_rn(__fsub_rn(fminf(px2, bx2[jj]), fmaxf(px1, bx1[jj])), 1.f);
        iw = fmaxf(0.f, iw);
        float ih = __fadd_rn(__fsub_rn(fminf(py2, by2[jj]), fmaxf(py1, by1[jj])), 1.f);
        ih = fmaxf(0.f, ih);
        float inter = __fmul_rn(iw, ih);
        float denom = __fsub_rn(__fadd_rn(pa, ar[jj]), inter);
        float iou = __fdiv_rn(inter, denom);
        if (iou > 0.7f) val[jj] = 0;
      }
    }
    __syncthreads();
  }

  __syncthreads();
  const int cnt = s_cnt;
  for (int t = cnt + tid; t < 300; t += 256) {
    float* row = out + ((size_t)b * 300 + t) * 5;
    row[0] = (float)b; row[1] = 0.f; row[2] = 0.f; row[3] = 0.f; row[4] = 0.f;
  }
  if (tid == 0) out[6000 + b] = (float)cnt;
}

// ---------------- launcher ----------------
extern "C" void kernel_launch(void* const* d_in, const int* in_sizes, int n_in,
                              void* d_out, int out_size, void* d_ws, size_t ws_size,
                              hipStream_t stream) {
  const float* x  = (const float*)d_in[0];
  const float* w1 = (const float*)d_in[1];
  const float* b1 = (const float*)d_in[2];
  const float* wb = (const float*)d_in[3];
  const float* bb = (const float*)d_in[4];
  const float* wc = (const float*)d_in[5];
  const float* bc = (const float*)d_in[6];
  float* out = (float*)d_out;
  char* ws = (char*)d_ws;

  float* feat   = (float*)(ws + 0);           // 31,457,280 B
  float* wt2    = (float*)(ws + 31457280);    //  9,437,184 B
  float* deltas = (float*)(ws + 40894464);    //  2,211,840 B
  float* s      = (float*)(ws + 43106304);    //    552,960 B
  float* boxes  = (float*)(ws + 43659264);    //  2,211,840 B
  u64*   keys   = (u64*)  (ws + 45871104);    //  1,105,920 B
  u64*   sel    = (u64*)  (ws + 46977088);    //     65,536 B

  hipLaunchKernelGGL(transpose_k, dim3(9216), dim3(256), 0, stream, w1, wt2);
  hipLaunchKernelGGL(conv1_k, dim3(16, 12, 4), dim3(256), 0, stream, x, wt2, b1, feat);
  hipLaunchKernelGGL(heads_k, dim3(312), dim3(256), 0, stream, feat, wb, bb, wc, bc, deltas, s);
  hipLaunchKernelGGL(decode_k, dim3(540), dim3(256), 0, stream, deltas, s, boxes, keys);
  hipLaunchKernelGGL(selcomp_k, dim3(4), dim3(1024), 0, stream, keys, sel);
  hipLaunchKernelGGL(nms2_k, dim3(4), dim3(256), 0, stream, sel, boxes, out);
}